// Round 10
// baseline (609.262 us; speedup 1.0000x reference)
//
#include <hip/hip_runtime.h>

#define TT 2048
#define BB 512
#define HH 64
#define NW 8
#define NTH (NW * 64)   // 512 threads
#define HIST 128        // history ring length
#define HPAD 68         // floats per hist row (272 B: 16B-aligned)

typedef float f32x2 __attribute__((ext_vector_type(2)));
typedef float f32x4 __attribute__((ext_vector_type(4)));

// quad/8-group DPP adds (ctrl literal)
#define DPP_ADD(v, ctrl) \
    ((v) + __int_as_float(__builtin_amdgcn_update_dpp(0, __float_as_int(v), (ctrl), 0xF, 0xF, false)))

__global__ __launch_bounds__(NTH, 1) void rnn_fused(
    const float* __restrict__ x,     // [T][B]
    const float* __restrict__ h0,    // [B][H]
    const float* __restrict__ Wih,   // [H]
    const float* __restrict__ Whh,   // [H][H]
    const float* __restrict__ bih,   // [H]
    const float* __restrict__ bhh,   // [H]
    const float* __restrict__ Wlin,  // [H]
    const float* __restrict__ blin,  // [1]
    float* __restrict__ y,           // [T][B]
    float* __restrict__ hN)          // [B][H]
{
    __shared__ __align__(16) float hist[HIST][HPAD];  // fp32 h ring
    __shared__ float xsh[TT + 4];                     // x column (+pad for t+1 probe)
    __shared__ __align__(16) float wlin_sh[HH];

    const int b    = blockIdx.x;
    const int tid  = threadIdx.x;
    const int lane = tid & 63;
    const int w    = tid >> 6;       // wave 0..7
    const int hl   = lane >> 3;      // 0..7
    const int ks   = lane & 7;       // K-split 0..7
    const int h    = w * 8 + hl;     // output index 0..63

    // ---- Prologue ----
    for (int i = tid; i < TT; i += NTH)
        xsh[i] = x[(size_t)i * BB + b];
    if (tid < 4) xsh[TT + tid] = 0.f;

    // W_hh[h][ks*8 .. ks*8+7] as 4 packed f32x2 in registers
    f32x2 wr[4];
    const float* wp = Whh + h * HH + ks * 8;
#pragma unroll
    for (int i = 0; i < 4; ++i) {
        wr[i][0] = wp[2 * i + 0];
        wr[i][1] = wp[2 * i + 1];
    }
    const float wih  = Wih[h];
    const float bias = bih[h] + bhh[h];
    const float bl   = blin[0];

    if (tid < HH) {
        hist[HIST - 1][tid] = h0[b * HH + tid];  // slot 127 = h_0
        wlin_sh[tid] = Wlin[tid];
    }
    __syncthreads();

    float hval = 0.f;
    float xw = fmaf(xsh[0], wih, bias);  // pipelined x-projection for step 0

    // ---- Recurrence: one barrier per step; bulk y every HIST steps ----
#pragma unroll 1
    for (int tc = 0; tc < TT; tc += HIST) {
#pragma unroll 2
        for (int ti = 0; ti < HIST; ++ti) {
            const int t  = tc + ti;
            const int rs = (ti + HIST - 1) & (HIST - 1);  // slot of h_{t-1}

            // my K=8 slice of h_prev: 2 x ds_read_b128 (broadcast across hl)
            const f32x4* hp = reinterpret_cast<const f32x4*>(&hist[rs][ks * 8]);
            const f32x4 q0 = hp[0], q1 = hp[1];

            // 4 v_pk_fma_f32 in 2 chains
            f32x2 a01 = {0.f, 0.f}, a23 = {0.f, 0.f};
            a01 = __builtin_elementwise_fma(__builtin_shufflevector(q0, q0, 0, 1), wr[0], a01);
            a23 = __builtin_elementwise_fma(__builtin_shufflevector(q0, q0, 2, 3), wr[1], a23);
            a01 = __builtin_elementwise_fma(__builtin_shufflevector(q1, q1, 0, 1), wr[2], a01);
            a23 = __builtin_elementwise_fma(__builtin_shufflevector(q1, q1, 2, 3), wr[3], a23);
            const f32x2 s2 = a01 + a23;
            float s = s2[0] + s2[1];

            // complete K=64 across the 8-lane ks group
            s = DPP_ADD(s, 0xB1);   // xor1 (quad_perm 1,0,3,2)
            s = DPP_ADD(s, 0x4E);   // xor2 (quad_perm 2,3,0,1)
            s = DPP_ADD(s, 0x141);  // half-row mirror = xor4 within 8-group

            const float acc = xw + s;

            // tanh(acc) = 1 - 2/(e^{2acc}+1); saturates correctly for large |acc|
            const float e2 = __expf(acc + acc);
            hval = 1.0f - __fdividef(2.0f, e2 + 1.0f);

            // publish h_t (8 contiguous lanes per wave)
            if (ks == 0) hist[ti][h] = hval;

            // pipelined x-projection for step t+1 — independent, hides under barrier
            xw = fmaf(xsh[t + 1], wih, bias);

            __syncthreads();
        }

        // ---- bulk y for this chunk: thread tid (<128) -> t = tc + tid ----
        if (tid < HIST) {
            const f32x4* hp = reinterpret_cast<const f32x4*>(&hist[tid][0]);
            const f32x4* wl = reinterpret_cast<const f32x4*>(&wlin_sh[0]);
            f32x2 acc2 = {0.f, 0.f};
#pragma unroll
            for (int i = 0; i < 16; ++i) {
                const f32x4 q  = hp[i];
                const f32x4 qw = wl[i];
                acc2 = __builtin_elementwise_fma(__builtin_shufflevector(q, q, 0, 1),
                                                 __builtin_shufflevector(qw, qw, 0, 1), acc2);
                acc2 = __builtin_elementwise_fma(__builtin_shufflevector(q, q, 2, 3),
                                                 __builtin_shufflevector(qw, qw, 2, 3), acc2);
            }
            y[(size_t)(tc + tid) * BB + b] = acc2[0] + acc2[1] + bl;
        }
        __syncthreads();  // protect ring from next chunk's writes
    }

    // ---- Epilogue ----
    if (ks == 0) hN[b * HH + h] = hval;
}

extern "C" void kernel_launch(void* const* d_in, const int* in_sizes, int n_in,
                              void* d_out, int out_size, void* d_ws, size_t ws_size,
                              hipStream_t stream) {
    const float* x    = (const float*)d_in[0];
    const float* h0   = (const float*)d_in[1];
    const float* Wih  = (const float*)d_in[2];
    const float* Whh  = (const float*)d_in[3];
    const float* bih  = (const float*)d_in[4];
    const float* bhh  = (const float*)d_in[5];
    const float* Wlin = (const float*)d_in[6];
    const float* blin = (const float*)d_in[7];

    float* y  = (float*)d_out;            // [T*B]
    float* hN = (float*)d_out + TT * BB;  // [B*H]

    rnn_fused<<<dim3(BB), dim3(NTH), 0, stream>>>(x, h0, Wih, Whh, bih, bhh, Wlin, blin, y, hN);
}

// Round 11
// 425.281 us; speedup vs baseline: 1.4326x; 1.4326x over previous
//
#include <hip/hip_runtime.h>

#define TT 2048
#define BB 512
#define HH 64
#define NW 4
#define NTH (NW * 64)   // 256 threads
#define HIST 128        // history ring length
#define HPAD 68         // floats per hist row (272 B: 16B-aligned)

typedef float f32x2 __attribute__((ext_vector_type(2)));
typedef float f32x4 __attribute__((ext_vector_type(4)));

// quad DPP adds (ctrl is a literal)
#define DPP_ADD(v, ctrl) \
    ((v) + __int_as_float(__builtin_amdgcn_update_dpp(0, __float_as_int(v), (ctrl), 0xF, 0xF, false)))

__global__ __launch_bounds__(NTH, 1) void rnn_fused(
    const float* __restrict__ x,     // [T][B]
    const float* __restrict__ h0,    // [B][H]
    const float* __restrict__ Wih,   // [H]
    const float* __restrict__ Whh,   // [H][H]
    const float* __restrict__ bih,   // [H]
    const float* __restrict__ bhh,   // [H]
    const float* __restrict__ Wlin,  // [H]
    const float* __restrict__ blin,  // [1]
    float* __restrict__ y,           // [T][B]
    float* __restrict__ hN)          // [B][H]
{
    __shared__ __align__(16) float hist[HIST][HPAD];  // fp32 h ring
    __shared__ float xsh[TT + 4];                     // x column (+pad for t+1 probe)
    __shared__ __align__(16) float wlin_sh[HH];

    const int b    = blockIdx.x;
    const int tid  = threadIdx.x;
    const int lane = tid & 63;
    const int w    = tid >> 6;       // wave 0..3
    const int hl   = lane >> 2;      // 0..15
    const int ks   = lane & 3;       // K-split 0..3
    const int h    = w * 16 + hl;    // output index 0..63

    // ---- Prologue ----
    for (int i = tid; i < TT; i += NTH)
        xsh[i] = x[(size_t)i * BB + b];
    if (tid < 4) xsh[TT + tid] = 0.f;

    // W_hh[h][ks*16 .. ks*16+15] as 8 packed f32x2 in registers
    f32x2 wr[8];
    const float* wp = Whh + h * HH + ks * 16;
#pragma unroll
    for (int i = 0; i < 8; ++i) {
        wr[i][0] = wp[2 * i + 0];
        wr[i][1] = wp[2 * i + 1];
    }
    const float wih  = Wih[h];
    const float bias = bih[h] + bhh[h];
    const float bl   = blin[0];

    if (tid < HH) {
        hist[HIST - 1][tid] = h0[b * HH + tid];  // slot 127 = h_0
        wlin_sh[tid] = Wlin[tid];
    }
    __syncthreads();

    float hval = 0.f;
    float xw = fmaf(xsh[0], wih, bias);  // pipelined x-projection for step 0

    // ---- Recurrence: one barrier per step; bulk y every HIST steps ----
#pragma unroll 1
    for (int tc = 0; tc < TT; tc += HIST) {
#pragma unroll 2
        for (int ti = 0; ti < HIST; ++ti) {
            const int t  = tc + ti;
            const int rs = (ti + HIST - 1) & (HIST - 1);  // slot of h_{t-1}

            // my K=16 slice of h_prev: 4 x ds_read_b128 (4 distinct addrs/wave,
            // broadcast across the 16 hl lanes)
            const f32x4* hp = reinterpret_cast<const f32x4*>(&hist[rs][ks * 16]);
            const f32x4 q0 = hp[0], q1 = hp[1], q2 = hp[2], q3 = hp[3];

            // 8 v_pk_fma_f32 in 4 independent chains
            f32x2 a01 = {0.f, 0.f}, a23 = {0.f, 0.f};
            f32x2 a45 = {0.f, 0.f}, a67 = {0.f, 0.f};
            a01 = __builtin_elementwise_fma(__builtin_shufflevector(q0, q0, 0, 1), wr[0], a01);
            a23 = __builtin_elementwise_fma(__builtin_shufflevector(q0, q0, 2, 3), wr[1], a23);
            a45 = __builtin_elementwise_fma(__builtin_shufflevector(q1, q1, 0, 1), wr[2], a45);
            a67 = __builtin_elementwise_fma(__builtin_shufflevector(q1, q1, 2, 3), wr[3], a67);
            a01 = __builtin_elementwise_fma(__builtin_shufflevector(q2, q2, 0, 1), wr[4], a01);
            a23 = __builtin_elementwise_fma(__builtin_shufflevector(q2, q2, 2, 3), wr[5], a23);
            a45 = __builtin_elementwise_fma(__builtin_shufflevector(q3, q3, 0, 1), wr[6], a45);
            a67 = __builtin_elementwise_fma(__builtin_shufflevector(q3, q3, 2, 3), wr[7], a67);
            const f32x2 s2 = (a01 + a23) + (a45 + a67);
            float s = s2[0] + s2[1];

            // complete K=64 across the 4-lane quad
            s = DPP_ADD(s, 0xB1);  // xor1
            s = DPP_ADD(s, 0x4E);  // xor2

            const float acc = xw + s;

            // tanh(acc) = 1 - 2/(e^{2acc}+1), e^{2acc} = 2^(acc * 2/ln2)
            const float e2 = __builtin_amdgcn_exp2f(acc * 2.885390081777927f);
            const float r  = __builtin_amdgcn_rcpf(e2 + 1.0f);
            hval = fmaf(-2.0f, r, 1.0f);

            // publish h_t into ring slot ti
            if (ks == 0) hist[ti][h] = hval;

            // pipelined x-projection for step t+1 — independent, hides under barrier
            xw = fmaf(xsh[t + 1], wih, bias);

            __syncthreads();
        }

        // ---- bulk y for this chunk: thread tid (<128) -> t = tc + tid ----
        if (tid < HIST) {
            const f32x4* hp = reinterpret_cast<const f32x4*>(&hist[tid][0]);
            const f32x4* wl = reinterpret_cast<const f32x4*>(&wlin_sh[0]);
            f32x2 acc2 = {0.f, 0.f};
#pragma unroll
            for (int i = 0; i < 16; ++i) {
                const f32x4 q  = hp[i];
                const f32x4 qw = wl[i];
                acc2 = __builtin_elementwise_fma(__builtin_shufflevector(q, q, 0, 1),
                                                 __builtin_shufflevector(qw, qw, 0, 1), acc2);
                acc2 = __builtin_elementwise_fma(__builtin_shufflevector(q, q, 2, 3),
                                                 __builtin_shufflevector(qw, qw, 2, 3), acc2);
            }
            y[(size_t)(tc + tid) * BB + b] = acc2[0] + acc2[1] + bl;
        }
        __syncthreads();  // protect ring from next chunk's writes
    }

    // ---- Epilogue ----
    if (ks == 0) hN[b * HH + h] = hval;
}

extern "C" void kernel_launch(void* const* d_in, const int* in_sizes, int n_in,
                              void* d_out, int out_size, void* d_ws, size_t ws_size,
                              hipStream_t stream) {
    const float* x    = (const float*)d_in[0];
    const float* h0   = (const float*)d_in[1];
    const float* Wih  = (const float*)d_in[2];
    const float* Whh  = (const float*)d_in[3];
    const float* bih  = (const float*)d_in[4];
    const float* bhh  = (const float*)d_in[5];
    const float* Wlin = (const float*)d_in[6];
    const float* blin = (const float*)d_in[7];

    float* y  = (float*)d_out;            // [T*B]
    float* hN = (float*)d_out + TT * BB;  // [B*H]

    rnn_fused<<<dim3(BB), dim3(NTH), 0, stream>>>(x, h0, Wih, Whh, bih, bhh, Wlin, blin, y, hN);
}

// Round 12
// 347.102 us; speedup vs baseline: 1.7553x; 1.2252x over previous
//
#include <hip/hip_runtime.h>

#define TT 2048
#define BB 512
#define HH 64
#define HIST 128        // history ring length
#define HPAD 68         // floats per hist row (272 B: 16B-aligned rows)

typedef float f32x2 __attribute__((ext_vector_type(2)));
typedef float f32x4 __attribute__((ext_vector_type(4)));

#define FMA2(a, b, c) __builtin_elementwise_fma((a), (b), (c))
#define LO2(q) __builtin_shufflevector((q), (q), 0, 1)
#define HI2(q) __builtin_shufflevector((q), (q), 2, 3)

// Single wave per block: no barriers anywhere. h-exchange is a same-wave LDS
// write -> uniform-broadcast read (DS pipe is in-order within a wave; pattern
// HW-validated in rounds 2/4).
__global__ __launch_bounds__(64, 1) void rnn_fused(
    const float* __restrict__ x,     // [T][B]
    const float* __restrict__ h0,    // [B][H]
    const float* __restrict__ Wih,   // [H]
    const float* __restrict__ Whh,   // [H][H]
    const float* __restrict__ bih,   // [H]
    const float* __restrict__ bhh,   // [H]
    const float* __restrict__ Wlin,  // [H]
    const float* __restrict__ blin,  // [1]
    float* __restrict__ y,           // [T][B]
    float* __restrict__ hN)          // [B][H]
{
    __shared__ __align__(16) float hist[HIST][HPAD];  // fp32 h ring
    __shared__ float xsh[TT + 4];                     // x column (+pad)
    __shared__ __align__(16) float wlin_sh[HH];

    const int b = blockIdx.x;   // batch column
    const int h = threadIdx.x;  // hidden index / lane, 0..63

    // ---- Prologue (single wave; in-order DS pipe, no barriers needed) ----
    for (int i = h; i < TT; i += 64)
        xsh[i] = x[(size_t)i * BB + b];
    if (h < 4) xsh[TT + h] = 0.f;

    // Full W_hh row for my h: 32 packed f32x2
    f32x2 wr[32];
    const float* wp = Whh + h * HH;
#pragma unroll
    for (int i = 0; i < 32; ++i) {
        wr[i][0] = wp[2 * i + 0];
        wr[i][1] = wp[2 * i + 1];
    }
    const float wih  = Wih[h];
    const float bias = bih[h] + bhh[h];
    const float bl   = blin[0];

    wlin_sh[h] = Wlin[h];
    hist[HIST - 1][h] = h0[b * HH + h];  // slot 127 = h_0

    float hval = 0.f;
    float xw = fmaf(xsh[0], wih, bias);  // x-projection for step 0 (off-chain)

    // ---- Recurrence ----
#pragma unroll 1
    for (int tc = 0; tc < TT; tc += HIST) {
#pragma unroll 4
        for (int ti = 0; ti < HIST; ++ti) {
            const int t  = tc + ti;
            const int rs = (ti + HIST - 1) & (HIST - 1);  // slot of h_{t-1}

            // h_prev via 16 wave-uniform ds_read_b128 (HW broadcast)
            const f32x4* hp = reinterpret_cast<const f32x4*>(&hist[rs][0]);

            // 32 v_pk_fma_f32 in 4 independent chains; xw folded into a01
            f32x2 a01 = {xw, 0.f}, a23 = {0.f, 0.f};
            f32x2 a45 = {0.f, 0.f}, a67 = {0.f, 0.f};
#pragma unroll
            for (int j = 0; j < 4; ++j) {
                const f32x4 p0 = hp[4 * j + 0];
                const f32x4 p1 = hp[4 * j + 1];
                const f32x4 p2 = hp[4 * j + 2];
                const f32x4 p3 = hp[4 * j + 3];
                a01 = FMA2(LO2(p0), wr[8 * j + 0], a01);
                a23 = FMA2(HI2(p0), wr[8 * j + 1], a23);
                a45 = FMA2(LO2(p1), wr[8 * j + 2], a45);
                a67 = FMA2(HI2(p1), wr[8 * j + 3], a67);
                a01 = FMA2(LO2(p2), wr[8 * j + 4], a01);
                a23 = FMA2(HI2(p2), wr[8 * j + 5], a23);
                a45 = FMA2(LO2(p3), wr[8 * j + 6], a45);
                a67 = FMA2(HI2(p3), wr[8 * j + 7], a67);
            }
            const f32x2 s2 = (a01 + a23) + (a45 + a67);
            const float acc = s2[0] + s2[1];

            // tanh(acc) = 1 - 2/(e^{2acc}+1), e^{2acc} = 2^(acc * 2/ln2)
            const float e2 = __builtin_amdgcn_exp2f(acc * 2.885390081777927f);
            const float r  = __builtin_amdgcn_rcpf(e2 + 1.0f);
            hval = fmaf(-2.0f, r, 1.0f);

            // publish h_t (64 contiguous lanes, 2-way bank alias = free)
            hist[ti][h] = hval;

            // x-projection for t+1 — independent, hides in read-latency shadow
            xw = fmaf(xsh[t + 1], wih, bias);
        }

        // ---- bulk y for this chunk: lane h handles slots h and h+64 ----
#pragma unroll 1
        for (int rep = 0; rep < 2; ++rep) {
            const int slot = rep * 64 + h;
            const f32x4* rp = reinterpret_cast<const f32x4*>(&hist[slot][0]);
            const f32x4* wl = reinterpret_cast<const f32x4*>(&wlin_sh[0]);
            f32x2 acc2 = {0.f, 0.f};
#pragma unroll
            for (int i = 0; i < 16; ++i) {
                const f32x4 q  = rp[i];
                const f32x4 qw = wl[i];
                acc2 = FMA2(LO2(q), LO2(qw), acc2);
                acc2 = FMA2(HI2(q), HI2(qw), acc2);
            }
            y[(size_t)(tc + slot) * BB + b] = acc2[0] + acc2[1] + bl;
        }
        // same wave: ring reuse next chunk is ordered after these reads — no barrier
    }

    // ---- Epilogue ----
    hN[b * HH + h] = hval;
}

extern "C" void kernel_launch(void* const* d_in, const int* in_sizes, int n_in,
                              void* d_out, int out_size, void* d_ws, size_t ws_size,
                              hipStream_t stream) {
    const float* x    = (const float*)d_in[0];
    const float* h0   = (const float*)d_in[1];
    const float* Wih  = (const float*)d_in[2];
    const float* Whh  = (const float*)d_in[3];
    const float* bih  = (const float*)d_in[4];
    const float* bhh  = (const float*)d_in[5];
    const float* Wlin = (const float*)d_in[6];
    const float* blin = (const float*)d_in[7];

    float* y  = (float*)d_out;            // [T*B]
    float* hN = (float*)d_out + TT * BB;  // [B*H]

    rnn_fused<<<dim3(BB), dim3(64), 0, stream>>>(x, h0, Wih, Whh, bih, bhh, Wlin, blin, y, hN);
}